// Round 1
// baseline (1260.502 us; speedup 1.0000x reference)
//
#include <hip/hip_runtime.h>
#include <stdint.h>

#define BETA 0.9f

// ---------------------------------------------------------------------------
// Kernel 1: transpose fw1 (256, 1152) -> fw1T (1152, 256) so the fc1 spike
// row-gather is coalesced (row i = 256 contiguous floats = 1KB).
// ---------------------------------------------------------------------------
__global__ void transpose_fw1(const float* __restrict__ A, float* __restrict__ At) {
    __shared__ float tile[32][33];
    const int i0 = blockIdx.x * 32;   // i dim (1152)
    const int j0 = blockIdx.y * 32;   // j dim (256)
    const int tx = threadIdx.x, ty = threadIdx.y;
    for (int r = ty; r < 32; r += 8)
        tile[r][tx] = A[(j0 + r) * 1152 + i0 + tx];      // coalesced read over i
    __syncthreads();
    for (int r = ty; r < 32; r += 8)
        At[(i0 + r) * 256 + j0 + tx] = tile[tx][r];      // coalesced write over j
}

// ---------------------------------------------------------------------------
// Kernel 2: whole SNN. R17: structural change vs R16:
//   * 1 element per block (384 threads, 6 waves), grid = 1024.
//   * fc1 rewritten from l-ownership (6 waves -> pacc -> b4 -> reduce -> b5)
//     to j-ownership: waves 0-3 own j=tid, walk ALL 18 masks, coalesced dword
//     gather, LIF4 inline. pacc + barrier b4 deleted. Addition tree preserved
//     exactly (per-group partial p, acc += p in g order; 0-padded batch adds).
//   * conv1(t+1) moves to waves 4-5 (3 outputs/thread, 9 prefetched x-loads),
//     running in fc1's shadow.
//   * LDS 53.2KB -> 37.8KB: 4 independent blocks/CU (24 waves) instead of 2
//     coupled 12-wave blocks. 3 barriers/t instead of 4.
// All FMA/add orders match R16 per output -> bit-exact (absmax 0.0 expected).
// ---------------------------------------------------------------------------
__global__ __launch_bounds__(384)
__attribute__((amdgpu_waves_per_eu(6)))
void snn_main(
    const float* __restrict__ x,      // (1024, 1, 30, 100)
    const float* __restrict__ w1, const float* __restrict__ b1,
    const float* __restrict__ w2, const float* __restrict__ b2,
    const float* __restrict__ w3, const float* __restrict__ b3,
    const float* __restrict__ fw1T,   // (1152, 256) transposed
    const float* __restrict__ fb1,
    const float* __restrict__ fw2, const float* __restrict__ fb2,
    float* __restrict__ out)          // (100, 1024, 10)
{
    const int b    = blockIdx.x;
    const int tid  = threadIdx.x;
    const int lane = tid & 63;               // hw-wave lane
    const int ew   = tid >> 6;               // wave 0..5

    __shared__ float w2L[16 * 5 * 32];  // [(ci*5+k)*32 + c2]  10 KB
    __shared__ float w3L[32 * 3 * 64];  // [(ci*3+k)*64 + c3]  24 KB
    __shared__ float s1e[16 * 24 + 8];
    __shared__ float s4[256];
    __shared__ unsigned long long masks[18];  // s3 spikes (bit = channel)
    __shared__ unsigned int rm1[2][16];  // s1 row masks (bit l), t-parity
    __shared__ unsigned int cm2[2][20];  // s2 per-l channel masks, t-parity

    // ---- static per-thread roles ----
    const int c2 = tid & 31;             // conv2: channel
    const int g2 = tid >> 5;             // conv2: l-group 0..11 (10,11 idle)
    const int l02 = 2 * g2;              // pair start
    const bool c2on = (tid < 320);       // exactly 10 groups x 32 ch
    const unsigned wmask2 = c2on ? (0x3Fu << l02) : 0u;
    const int c3 = lane;                 // conv3: out channel
    const int l03 = ew * 3;              // conv3: 3 positions per wave

    // conv1 roles (waves 4,5: 128 threads, 3 outputs each)
    const int tl2 = tid - 256;           // valid when tid>=256
    const int c1 = tl2 & 15;
    const int l1 = (tl2 >> 4) * 3;       // base l: {0,3,...,21}

    // ---- stage weights into LDS ----
    for (int i = tid; i < 16 * 5 * 32; i += 384) {
        const int cc = i & 31, r = i >> 5;          // r = ci*5+k
        w2L[i] = w2[cc * 80 + r];
    }
    for (int i = tid; i < 32 * 3 * 64; i += 384) {
        const int cc = i & 63, r = i >> 6;          // r = ci*3+k
        w3L[i] = w3[cc * 96 + r];
    }
    if (tid < 16) { rm1[0][tid] = 0u; rm1[1][tid] = 0u; }
    if (tid < 20) { cm2[0][tid] = 0u; cm2[1][tid] = 0u; }
    if (tid < 8)  s1e[384 + tid] = 0.0f;

    // ---- per-thread register state ----
    const float* xb = x + b * 3000;
    float w1r[7];
    float b1r = 0.0f;
    float xr[9];
    if (tid >= 256) {
#pragma unroll
        for (int k = 0; k < 7; ++k) w1r[k] = w1[c1 * 7 + k];
        b1r = b1[c1];
        // x register load for t=0 (overlaps the staging barrier)
#pragma unroll
        for (int k = 0; k < 9; ++k) xr[k] = xb[(l1 + k) * 100];
    }
    const float b2r = b2[c2];
    const float b3r = b3[c3];
    const float fb1r = (tid < 256) ? fb1[tid] : 0.0f;
    const int jf = tid >> 4, chf = tid & 15;           // fc2 roles (tid<160)
    const float fb2r = (tid < 160 && chf == 0) ? fb2[jf] : 0.0f;

    float m1[3] = {0.f, 0.f, 0.f};
    float m2[2] = {0.f, 0.f};
    float m3[3] = {0.f, 0.f, 0.f};
    float m4 = 0.f, m5 = 0.f;

    const int out_b = b * 10;

    __syncthreads();   // staging -> compute

    // ---- peeled conv1(t=0) on waves 4,5 ----
    if (tid >= 256) {
#pragma unroll
        for (int j = 0; j < 3; ++j) {
            float h = b1r;
#pragma unroll
            for (int k = 0; k < 7; ++k) h += xr[j + k] * w1r[k];
            float rs = (m1[j] > 1.0f) ? 1.0f : 0.0f;
            m1[j] = BETA * m1[j] + h - rs;
            float sa = (m1[j] > 1.0f) ? 1.0f : 0.0f;
            s1e[c1 * 24 + l1 + j] = sa;
            if (sa != 0.0f) atomicOr(&rm1[0][c1], 1u << (l1 + j));
        }
    }
    __syncthreads();   // conv1(0) -> conv2(0)

    for (int t = 0; t < 100; ++t) {
        const int pb = t & 1, pn = pb ^ 1;

        // ---- conv2 + LIF2 (rm1 row-skip, scalar win reads) ----
        {
            if (tid < 16) rm1[pn][tid] = 0u;   // zero other parity for t+1
            if (tid < 20) cm2[pn][tid] = 0u;
            // issue x(t+1) loads early: consumed by conv1(t+1) after b3
            if (t < 99 && tid >= 256) {
#pragma unroll
                for (int k = 0; k < 9; ++k) xr[k] = xb[(l1 + k) * 100 + t + 1];
            }
            float h[2] = {b2r, b2r};
#pragma unroll
            for (int ci = 0; ci < 16; ++ci) {
                const unsigned rmv =
                    __builtin_amdgcn_readfirstlane(rm1[pb][ci]);
                if ((rmv & wmask2) == 0u) continue;   // exact: skipped terms 0*w
                float win[6];
#pragma unroll
                for (int r = 0; r < 6; ++r) win[r] = s1e[ci * 24 + l02 + r];
                float wk[5];
#pragma unroll
                for (int k = 0; k < 5; ++k) wk[k] = w2L[(ci * 5 + k) * 32 + c2];
#pragma unroll
                for (int li = 0; li < 2; ++li)
#pragma unroll
                    for (int k = 0; k < 5; ++k) h[li] += win[li + k] * wk[k];
            }
            if (c2on) {
#pragma unroll
                for (int li = 0; li < 2; ++li) {
                    float rs = (m2[li] > 1.0f) ? 1.0f : 0.0f;
                    m2[li] = BETA * m2[li] + h[li] - rs;
                    if (m2[li] > 1.0f) atomicOr(&cm2[pb][l02 + li], 1u << c2);
                }
            }
        }
        __syncthreads();   // b2

        // ---- conv3 + LIF3: spike-driven gather (wave-uniform, nl3=3) ----
        {
            float h[3] = {b3r, b3r, b3r};
#pragma unroll
            for (int wl = 0; wl < 5; ++wl) {   // window positions l03..l03+4
                unsigned cm = __builtin_amdgcn_readfirstlane(cm2[pb][l03 + wl]);
                while (cm) {               // scalar mask walk
                    const int ci = (int)__builtin_ctz(cm); cm &= cm - 1;
                    const float* wp = &w3L[ci * 192 + c3];   // + k*64
#pragma unroll
                    for (int k = 0; k < 3; ++k) {
                        const int li = wl - k;               // compile-time
                        if (li >= 0 && li < 3)
                            h[li] += wp[k * 64];             // ds_read imm offset
                    }
                }
            }
#pragma unroll
            for (int li = 0; li < 3; ++li) {
                float rs = (m3[li] > 1.0f) ? 1.0f : 0.0f;
                m3[li] = BETA * m3[li] + h[li] - rs;
                float s = (m3[li] > 1.0f) ? 1.0f : 0.0f;
                unsigned long long mk = __ballot(s != 0.0f);
                if (lane == 0) masks[l03 + li] = mk;
            }
        }
        __syncthreads();   // b3

        // ---- fc1 phase: waves 0-3 j-ownership gather + LIF4 inline;
        //      waves 4-5 run conv1(t+1) in its shadow. No pacc, no b4. ----
        if (tid >= 256) {
            if (t < 99) {
#pragma unroll
                for (int j = 0; j < 3; ++j) {
                    float h = b1r;
#pragma unroll
                    for (int k = 0; k < 7; ++k) h += xr[j + k] * w1r[k];
                    float rs = (m1[j] > 1.0f) ? 1.0f : 0.0f;
                    m1[j] = BETA * m1[j] + h - rs;
                    float sa = (m1[j] > 1.0f) ? 1.0f : 0.0f;
                    s1e[c1 * 24 + l1 + j] = sa;
                    if (sa != 0.0f) atomicOr(&rm1[pn][c1], 1u << (l1 + j));
                }
            }
        } else {
            // exact R16 addition tree per output j = tid:
            //   acc = fb1 + P0 + ... + P5,  Pg = sum over l in {g,g+6,g+12}
            //   of spikes in ascending-c order (0-padded adds are bitwise no-ops)
            float acc = fb1r;
#pragma unroll 1
            for (int g = 0; g < 6; ++g) {
                float p = 0.f;
#pragma unroll 1
                for (int li3 = 0; li3 < 3; ++li3) {
                    const int l = g + 6 * li3;
                    const unsigned* mp = (const unsigned*)&masks[l];
                    const unsigned mlo = __builtin_amdgcn_readfirstlane(mp[0]);
                    const unsigned mhi = __builtin_amdgcn_readfirstlane(mp[1]);
                    unsigned long long mk =
                        ((unsigned long long)mhi << 32) | mlo;
                    while (mk) {   // 8-wide batching: 8 loads in flight
                        float f0=0.f,f1=0.f,f2=0.f,f3=0.f;
                        float f4=0.f,f5=0.f,f6=0.f,f7=0.f;
                        int c;
                        c = (int)__builtin_ctzll(mk); mk &= mk - 1;
                        f0 = (fw1T + (c * 18 + l) * 256)[tid];
                        if (mk) { c = (int)__builtin_ctzll(mk); mk &= mk - 1;
                                  f1 = (fw1T + (c * 18 + l) * 256)[tid]; }
                        if (mk) { c = (int)__builtin_ctzll(mk); mk &= mk - 1;
                                  f2 = (fw1T + (c * 18 + l) * 256)[tid]; }
                        if (mk) { c = (int)__builtin_ctzll(mk); mk &= mk - 1;
                                  f3 = (fw1T + (c * 18 + l) * 256)[tid]; }
                        if (mk) { c = (int)__builtin_ctzll(mk); mk &= mk - 1;
                                  f4 = (fw1T + (c * 18 + l) * 256)[tid]; }
                        if (mk) { c = (int)__builtin_ctzll(mk); mk &= mk - 1;
                                  f5 = (fw1T + (c * 18 + l) * 256)[tid]; }
                        if (mk) { c = (int)__builtin_ctzll(mk); mk &= mk - 1;
                                  f6 = (fw1T + (c * 18 + l) * 256)[tid]; }
                        if (mk) { c = (int)__builtin_ctzll(mk); mk &= mk - 1;
                                  f7 = (fw1T + (c * 18 + l) * 256)[tid]; }
                        p += f0; p += f1; p += f2; p += f3;
                        p += f4; p += f5; p += f6; p += f7;
                    }
                }
                acc += p;
            }
            // LIF4 inline (thread tid owns output j=tid) -- no barrier needed
            float rs = (m4 > 1.0f) ? 1.0f : 0.0f;
            m4 = BETA * m4 + acc - rs;
            s4[tid] = (m4 > 1.0f) ? 1.0f : 0.0f;
        }
        __syncthreads();   // b5

        // ---- fc2 fused: 10 outputs, 16 lanes each, shuffle reduce ----
        if (tid < 160) {
            const float* wrow = fw2 + jf * 256;   // L1-hot (10KB, reused)
            float p = 0.f;
#pragma unroll
            for (int i = 0; i < 16; ++i)
                p += s4[i * 16 + chf] * wrow[i * 16 + chf];
            p += __shfl_xor(p, 8, 16);
            p += __shfl_xor(p, 4, 16);
            p += __shfl_xor(p, 2, 16);
            p += __shfl_xor(p, 1, 16);
            if (chf == 0) {
                float h = fb2r + p;
                float rs = (m5 > 1.0f) ? 1.0f : 0.0f;
                m5 = BETA * m5 + h - rs;
                out[t * 10240 + out_b + jf] = (m5 > 1.0f) ? 1.0f : 0.0f;
            }
        }
        // no trailing barrier: conv2(t+1) inputs (s1e, rm1[pn]) were written
        // before b5; s4's next write sits behind b2+b3 of t+1; cm2/rm1 zeroing
        // targets were last read before b2/b3 of this t.
    }
}

extern "C" void kernel_launch(void* const* d_in, const int* in_sizes, int n_in,
                              void* d_out, int out_size, void* d_ws, size_t ws_size,
                              hipStream_t stream) {
    const float* x   = (const float*)d_in[0];
    const float* w1  = (const float*)d_in[1];
    const float* b1  = (const float*)d_in[2];
    const float* w2  = (const float*)d_in[3];
    const float* b2  = (const float*)d_in[4];
    const float* w3  = (const float*)d_in[5];
    const float* b3  = (const float*)d_in[6];
    const float* fw1 = (const float*)d_in[7];
    const float* fb1 = (const float*)d_in[8];
    const float* fw2 = (const float*)d_in[9];
    const float* fb2 = (const float*)d_in[10];
    float* out  = (float*)d_out;
    float* fw1T = (float*)d_ws;   // 1152*256*4 = 1.18 MB

    dim3 tb(32, 8);
    dim3 tg(1152 / 32, 256 / 32);
    transpose_fw1<<<tg, tb, 0, stream>>>(fw1, fw1T);
    snn_main<<<1024, 384, 0, stream>>>(x, w1, b1, w2, b2, w3, b3,
                                       fw1T, fb1, fw2, fb2, out);
}